// Round 8
// baseline (70.837 us; speedup 1.0000x reference)
//
#include <hip/hip_runtime.h>
#include <math.h>

constexpr int D  = 768;
constexpr int NQ = 8;
constexpr int B  = 32;
constexpr int NP = 196;      // n_patch
constexpr int KT = 7;        // K tiles of 32
constexpr int KP = KT * 32;  // 224 padded K
constexpr int TPAD = 776;    // LDS tile row stride (shorts)
constexpr int NT_OFF = 120;  // off-diag 2x2 pair tiles (it<jt over 16)
constexpr int NTILES = 136;  // + 16 diagonal tiles
constexpr float EPS = 1e-5f;
constexpr float INV_SQRT_D = 0.036084391824351615f;  // 1/sqrt(768)

typedef __attribute__((ext_vector_type(8))) short short8;
typedef __attribute__((ext_vector_type(4))) float f32x4;

__device__ __forceinline__ float wave_reduce_sum(float v) {
#pragma unroll
    for (int off = 32; off > 0; off >>= 1) v += __shfl_xor(v, off, 64);
    return v;
}
__device__ __forceinline__ float wave_reduce_max(float v) {
#pragma unroll
    for (int off = 32; off > 0; off >>= 1) v = fmaxf(v, __shfl_xor(v, off, 64));
    return v;
}

__device__ __forceinline__ unsigned short f2bf(float x) {
    union { float f; unsigned u; } c; c.f = x;
    unsigned r = c.u + 0x7fffu + ((c.u >> 16) & 1u);   // RNE
    return (unsigned short)(r >> 16);
}

// Fused: LN(q) in-reg + LN(kv 16-row half-tile) + scores S + frag-layout pack.
// kvTf[b][dt:48][kt:7][slot:64][e:8], value = kvn[kt*32+kg*8+e][dt*16+dl],
// slot = kg*16+dl.  One block per (b, h) with h in [0,14): rows [h*16,h*16+16).
__global__ __launch_bounds__(256) void kv_fused(const float* __restrict__ q_x,
                                                const float* __restrict__ qw,
                                                const float* __restrict__ qb,
                                                const float* __restrict__ kv_x,
                                                const float* __restrict__ kw,
                                                const float* __restrict__ kb,
                                                float* __restrict__ S,
                                                unsigned short* __restrict__ kvTf) {
    const int b = blockIdx.x / 14;
    const int h = blockIdx.x % 14;
    const int kt = h >> 1;
    const int kgbase = (h & 1) * 2;
    const int tid = threadIdx.x, wave = tid >> 6, lane = tid & 63;
    __shared__ unsigned short tile[16][TPAD];  // 24.8 KB

    const bool live = (h * 16) < NP;

    float wv[12], bv[12];
#pragma unroll
    for (int c = 0; c < 12; ++c) { wv[c] = kw[lane + 64 * c]; bv[c] = kb[lane + 64 * c]; }

    float qreg[NQ][12];
    if (live) {
        float wqv[12], bqv[12];
#pragma unroll
        for (int c = 0; c < 12; ++c) { wqv[c] = qw[lane + 64 * c]; bqv[c] = qb[lane + 64 * c]; }
#pragma unroll
        for (int q = 0; q < NQ; ++q) {
            float v[12];
            float s = 0.f;
#pragma unroll
            for (int c = 0; c < 12; ++c) { v[c] = q_x[q * D + lane + 64 * c]; s += v[c]; }
            s = wave_reduce_sum(s);
            const float mean = s * (1.0f / D);
            float ss = 0.f;
#pragma unroll
            for (int c = 0; c < 12; ++c) { v[c] -= mean; ss += v[c] * v[c]; }
            ss = wave_reduce_sum(ss);
            const float rs = rsqrtf(ss * (1.0f / D) + EPS);
#pragma unroll
            for (int c = 0; c < 12; ++c) qreg[q][c] = v[c] * rs * wqv[c] + bqv[c];
        }
    }

    for (int r = 0; r < 4; ++r) {
        const int nl = wave * 4 + r;
        const int n  = h * 16 + nl;
        if (n < NP) {
            const float* xr = kv_x + ((size_t)b * NP + n) * D;
            float v[12];
            float s = 0.f;
#pragma unroll
            for (int c = 0; c < 12; ++c) { v[c] = xr[lane + 64 * c]; s += v[c]; }
            s = wave_reduce_sum(s);
            const float mean = s * (1.0f / D);
            float ss = 0.f;
#pragma unroll
            for (int c = 0; c < 12; ++c) { v[c] -= mean; ss += v[c] * v[c]; }
            ss = wave_reduce_sum(ss);
            const float rs = rsqrtf(ss * (1.0f / D) + EPS);
            float y[12];
#pragma unroll
            for (int c = 0; c < 12; ++c) {
                y[c] = v[c] * rs * wv[c] + bv[c];
                tile[nl][lane + 64 * c] = f2bf(y[c]);
            }
#pragma unroll
            for (int q = 0; q < NQ; ++q) {
                float dq = 0.f;
#pragma unroll
                for (int c = 0; c < 12; ++c) dq += y[c] * qreg[q][c];
                dq = wave_reduce_sum(dq);
                if (lane == 0) S[((size_t)b * NQ + q) * NP + n] = dq * INV_SQRT_D;
            }
        } else {
#pragma unroll
            for (int c = 0; c < 12; ++c) tile[nl][lane + 64 * c] = 0;
        }
    }
    __syncthreads();

    // frag-layout store: 48 dt * 32 local slots = 1536 chunks of 16B, 6/thread.
#pragma unroll
    for (int rep = 0; rep < 6; ++rep) {
        const int chunk = rep * 256 + tid;
        const int dt = chunk >> 5, ls = chunk & 31;
        const int hi = ls >> 4, dl = ls & 15;
        const int kg = kgbase + hi;
        short8 vals;
#pragma unroll
        for (int e = 0; e < 8; ++e)
            vals[e] = (short)tile[hi * 8 + e][dt * 16 + dl];
        *(short8*)(kvTf + ((((size_t)b * 48 + dt) * KT + kt) * 64 + kg * 16 + dl) * 8) = vals;
    }
}

// 2x2-pair-tiled one-pass GEMM with fused softmax.
// Tile t: off-diag (it<jt): pairs g in [0,4): i = 2it+(g>>1), j = 2jt+(g&1).
//         diag (it==jt): valid pair at g==1 (i=2it, j=2it+1); g==0/3 write
//         diagonal zeros; g==2 idle.
// Block = (tile, nb of 8): 96-col slice. 8 waves = 4 pairs x 2 sub-slices.
// acc = A @ kv_i + (-A) @ kv_j; rows dir0 -> out[i*B+j], dir1 -> -acc.
__global__ __launch_bounds__(512) void dgemm(const float* __restrict__ S,
                                             const unsigned short* __restrict__ kvTf,
                                             float* __restrict__ out) {
    // XCD-bijective swizzle: 1088 = 8 * 136, siblings land on one XCD's L2.
    const int bid = blockIdx.x;
    const int lb  = (bid & 7) * NTILES + (bid >> 3);
    const int nb  = lb & 7;
    int t = lb >> 3;

    int it, jt;
    bool diag;
    if (t < NT_OFF) {
        int tt = t, a = 0;
        while (tt >= 15 - a) { tt -= 15 - a; ++a; }
        it = a; jt = a + 1 + tt; diag = false;
    } else {
        it = jt = t - NT_OFF; diag = true;
    }

    const int tid = threadIdx.x, wave = tid >> 6, lane = tid & 63;
    __shared__ unsigned short a2[4][KT][64][8];  // 28 KB

    // ---- softmax: 64 rows (4 pairs x 2 dirs x 8 q); 8 rows per wave ----
    for (int rr = 0; rr < 8; ++rr) {
        const int r = wave * 8 + rr;
        const int g = r >> 4, lr = r & 15, dir = lr >> 3, q = lr & 7;
        const int i = 2 * it + (g >> 1), j = 2 * jt + (g & 1);
        const float* Sa = S + ((size_t)(dir ? j : i) * NQ + q) * NP;
        const float* Sb = S + ((size_t)(dir ? i : j) * NQ + q) * NP;
        float v[4];
        float m = -1e30f;
#pragma unroll
        for (int c = 0; c < 4; ++c) {
            const int n = lane + 64 * c;
            v[c] = (n < NP) ? (Sa[n] - Sb[n]) : -1e30f;
            m = fmaxf(m, v[c]);
        }
        m = wave_reduce_max(m);
        float e[4];
        float sum = 0.f;
#pragma unroll
        for (int c = 0; c < 4; ++c) {
            const int n = lane + 64 * c;
            e[c] = (n < NP) ? __expf(v[c] - m) : 0.f;
            sum += e[c];
        }
        sum = wave_reduce_sum(sum);
        const float rinv = 1.0f / sum;
#pragma unroll
        for (int c = 0; c < 4; ++c) {
            const int n = lane + 64 * c;
            if (n < KP) {
                const unsigned short w16 = (n < NP) ? f2bf(e[c] * rinv) : (unsigned short)0;
                a2[g][n >> 5][((n >> 3) & 3) * 16 + lr][n & 7] = w16;
            }
        }
    }
    __syncthreads();

    const int g = wave >> 1, s = wave & 1;

    if (diag && g != 1) {
        if (g == 0 || g == 3) {          // exact-zero diagonal outputs
            const int ii = 2 * it + (g == 3 ? 1 : 0);
            const int p = ii * B + ii;
            if (lane < 48) {
                float* op = out + (size_t)p * NQ * D + nb * 96 + s * 48 + lane;
#pragma unroll
                for (int q = 0; q < NQ; ++q) op[q * D] = 0.f;
            }
        }
        return;
    }

    const int i = 2 * it + (g >> 1), j = 2 * jt + (g & 1);
    const int dtb = nb * 6 + s * 3;

    const unsigned short* Ki = kvTf + (size_t)i * 48 * KT * 512 + (size_t)lane * 8;
    const unsigned short* Kj = kvTf + (size_t)j * 48 * KT * 512 + (size_t)lane * 8;

    f32x4 acc[3];
#pragma unroll
    for (int nf = 0; nf < 3; ++nf) {
        f32x4 z = {0.f, 0.f, 0.f, 0.f};
        acc[nf] = z;
    }

#pragma unroll
    for (int kt = 0; kt < KT; ++kt) {
        short8 a = *(const short8*)(&a2[g][kt][lane][0]);
        short8 na;
#pragma unroll
        for (int e = 0; e < 8; ++e) na[e] = (short)(a[e] ^ (short)0x8000);
#pragma unroll
        for (int nf = 0; nf < 3; ++nf) {
            const int dt = dtb + nf;
            short8 ki = *(const short8*)(Ki + ((size_t)dt * KT + kt) * 512);
            short8 kj = *(const short8*)(Kj + ((size_t)dt * KT + kt) * 512);
            acc[nf] = __builtin_amdgcn_mfma_f32_16x16x32_bf16(a,  ki, acc[nf], 0, 0, 0);
            acc[nf] = __builtin_amdgcn_mfma_f32_16x16x32_bf16(na, kj, acc[nf], 0, 0, 0);
        }
    }

    // ---- epilogue: C row-in-tile = (lane>>4)*4 + reg, col = lane&15 ----
    const int kgrp = lane >> 4, dl = lane & 15;
    const int pij = i * B + j, pji = j * B + i;
#pragma unroll
    for (int reg = 0; reg < 4; ++reg) {
        const int r = kgrp * 4 + reg;
        const int dirr = r >> 3, qq = r & 7;
        const int p = dirr ? pji : pij;
        const float sgn = dirr ? -1.f : 1.f;
        float* op = out + ((size_t)p * NQ + qq) * D + nb * 96 + s * 48 + dl;
#pragma unroll
        for (int nf = 0; nf < 3; ++nf) op[nf * 16] = sgn * acc[nf][reg];
    }
}

extern "C" void kernel_launch(void* const* d_in, const int* in_sizes, int n_in,
                              void* d_out, int out_size, void* d_ws, size_t ws_size,
                              hipStream_t stream) {
    const float* q_x     = (const float*)d_in[0];
    const float* kv_x    = (const float*)d_in[1];
    const float* ln_q_w  = (const float*)d_in[2];
    const float* ln_q_b  = (const float*)d_in[3];
    const float* ln_kv_w = (const float*)d_in[4];
    const float* ln_kv_b = (const float*)d_in[5];
    float* out = (float*)d_out;

    float* ws = (float*)d_ws;
    float* S  = ws;                                             // 32*8*196 f32
    unsigned short* kvTf = (unsigned short*)(ws + B * NQ * NP);  // 32*48*7*512 bf16

    kv_fused<<<B * 14, 256, 0, stream>>>(q_x, ln_q_w, ln_q_b, kv_x, ln_kv_w, ln_kv_b, S, kvTf);
    dgemm<<<NTILES * 8, 512, 0, stream>>>(S, kvTf, out);
}

// Round 10
// 53.477 us; speedup vs baseline: 1.3246x; 1.3246x over previous
//
#include <hip/hip_runtime.h>
#include <math.h>

constexpr int D  = 768;
constexpr int NQ = 8;
constexpr int B  = 32;
constexpr int NP = 196;      // n_patch
constexpr int KT = 7;        // K tiles of 32
constexpr int KP = KT * 32;  // 224 padded K
constexpr int TPAD = 776;    // LDS tile row stride (shorts)
constexpr float EPS = 1e-5f;
constexpr float INV_SQRT_D = 0.036084391824351615f;  // 1/sqrt(768)

typedef __attribute__((ext_vector_type(8))) short short8;
typedef __attribute__((ext_vector_type(4))) float f32x4;

__device__ __forceinline__ float wave_reduce_sum(float v) {
#pragma unroll
    for (int off = 32; off > 0; off >>= 1) v += __shfl_xor(v, off, 64);
    return v;
}
__device__ __forceinline__ float wave_reduce_max(float v) {
#pragma unroll
    for (int off = 32; off > 0; off >>= 1) v = fmaxf(v, __shfl_xor(v, off, 64));
    return v;
}

__device__ __forceinline__ unsigned short f2bf(float x) {
    union { float f; unsigned u; } c; c.f = x;
    unsigned r = c.u + 0x7fffu + ((c.u >> 16) & 1u);   // RNE
    return (unsigned short)(r >> 16);
}

// Fused: LN(q) in-reg + LN(kv 16-row half-tile) + scores S + frag-layout pack.
// kvTf[b][dt:48][kt:7][slot:64][e:8], value = kvn[kt*32+kg*8+e][dt*16+dl],
// slot = kg*16+dl.  One block per (b, h) with h in [0,14): rows [h*16,h*16+16).
__global__ __launch_bounds__(256) void kv_fused(const float* __restrict__ q_x,
                                                const float* __restrict__ qw,
                                                const float* __restrict__ qb,
                                                const float* __restrict__ kv_x,
                                                const float* __restrict__ kw,
                                                const float* __restrict__ kb,
                                                float* __restrict__ S,
                                                unsigned short* __restrict__ kvTf) {
    const int b = blockIdx.x / 14;
    const int h = blockIdx.x % 14;
    const int kt = h >> 1;
    const int kgbase = (h & 1) * 2;
    const int tid = threadIdx.x, wave = tid >> 6, lane = tid & 63;
    __shared__ unsigned short tile[16][TPAD];  // 24.8 KB

    const bool live = (h * 16) < NP;

    float wv[12], bv[12];
#pragma unroll
    for (int c = 0; c < 12; ++c) { wv[c] = kw[lane + 64 * c]; bv[c] = kb[lane + 64 * c]; }

    float qreg[NQ][12];
    if (live) {
        float wqv[12], bqv[12];
#pragma unroll
        for (int c = 0; c < 12; ++c) { wqv[c] = qw[lane + 64 * c]; bqv[c] = qb[lane + 64 * c]; }
#pragma unroll
        for (int q = 0; q < NQ; ++q) {
            float v[12];
            float s = 0.f;
#pragma unroll
            for (int c = 0; c < 12; ++c) { v[c] = q_x[q * D + lane + 64 * c]; s += v[c]; }
            s = wave_reduce_sum(s);
            const float mean = s * (1.0f / D);
            float ss = 0.f;
#pragma unroll
            for (int c = 0; c < 12; ++c) { v[c] -= mean; ss += v[c] * v[c]; }
            ss = wave_reduce_sum(ss);
            const float rs = rsqrtf(ss * (1.0f / D) + EPS);
#pragma unroll
            for (int c = 0; c < 12; ++c) qreg[q][c] = v[c] * rs * wqv[c] + bqv[c];
        }
    }

    for (int r = 0; r < 4; ++r) {
        const int nl = wave * 4 + r;
        const int n  = h * 16 + nl;
        if (n < NP) {
            const float* xr = kv_x + ((size_t)b * NP + n) * D;
            float v[12];
            float s = 0.f;
#pragma unroll
            for (int c = 0; c < 12; ++c) { v[c] = xr[lane + 64 * c]; s += v[c]; }
            s = wave_reduce_sum(s);
            const float mean = s * (1.0f / D);
            float ss = 0.f;
#pragma unroll
            for (int c = 0; c < 12; ++c) { v[c] -= mean; ss += v[c] * v[c]; }
            ss = wave_reduce_sum(ss);
            const float rs = rsqrtf(ss * (1.0f / D) + EPS);
            float y[12];
#pragma unroll
            for (int c = 0; c < 12; ++c) {
                y[c] = v[c] * rs * wv[c] + bv[c];
                tile[nl][lane + 64 * c] = f2bf(y[c]);
            }
#pragma unroll
            for (int q = 0; q < NQ; ++q) {
                float dq = 0.f;
#pragma unroll
                for (int c = 0; c < 12; ++c) dq += y[c] * qreg[q][c];
                dq = wave_reduce_sum(dq);
                if (lane == 0) S[((size_t)b * NQ + q) * NP + n] = dq * INV_SQRT_D;
            }
        } else {
#pragma unroll
            for (int c = 0; c < 12; ++c) tile[nl][lane + 64 * c] = 0;
        }
    }
    __syncthreads();

    // frag-layout store: 48 dt * 32 local slots = 1536 chunks of 16B, 6/thread.
#pragma unroll
    for (int rep = 0; rep < 6; ++rep) {
        const int chunk = rep * 256 + tid;
        const int dt = chunk >> 5, ls = chunk & 31;
        const int hi = ls >> 4, dl = ls & 15;
        const int kg = kgbase + hi;
        short8 vals;
#pragma unroll
        for (int e = 0; e < 8; ++e)
            vals[e] = (short)tile[hi * 8 + e][dt * 16 + dl];
        *(short8*)(kvTf + ((((size_t)b * 48 + dt) * KT + kt) * 64 + kg * 16 + dl) * 8) = vals;
    }
}

// Softmax once per unordered pair u={i<j}: 16 rows r = dir*8+q
// (dir0 = softmax(S_i - S_j), dir1 = softmax(S_j - S_i)), written bf16 in
// MFMA-frag layout Abf[u][kt:7][slot:64][e:8], slot = kg*16 + r.
__global__ __launch_bounds__(512) void aprep(const float* __restrict__ S,
                                             unsigned short* __restrict__ Abf) {
    const int u = blockIdx.x;
    int uu = u, i = 0;
    while (uu >= 31 - i) { uu -= 31 - i; ++i; }
    const int j = i + 1 + uu;

    const int tid = threadIdx.x, wave = tid >> 6, lane = tid & 63;
    __shared__ unsigned short lrow[16][KP];  // 7 KB

    for (int jj = 0; jj < 2; ++jj) {
        const int r = wave * 2 + jj;          // 0..15
        const int dir = r >> 3, q = r & 7;
        const float* Sa = S + ((size_t)(dir ? j : i) * NQ + q) * NP;
        const float* Sb = S + ((size_t)(dir ? i : j) * NQ + q) * NP;
        float v[4];
        float m = -1e30f;
#pragma unroll
        for (int c = 0; c < 4; ++c) {
            const int n = lane + 64 * c;
            v[c] = (n < NP) ? (Sa[n] - Sb[n]) : -1e30f;
            m = fmaxf(m, v[c]);
        }
        m = wave_reduce_max(m);
        float e[4];
        float sum = 0.f;
#pragma unroll
        for (int c = 0; c < 4; ++c) {
            const int n = lane + 64 * c;
            e[c] = (n < NP) ? __expf(v[c] - m) : 0.f;
            sum += e[c];
        }
        sum = wave_reduce_sum(sum);
        const float rinv = 1.0f / sum;
#pragma unroll
        for (int c = 0; c < 4; ++c) {
            const int n = lane + 64 * c;
            if (n < KP) lrow[r][n] = (n < NP) ? f2bf(e[c] * rinv) : (unsigned short)0;
        }
    }
    __syncthreads();

    // frag write: 7 kt * 64 slots = 448 chunks of 16B
    if (tid < 448) {
        const int kt = tid >> 6, slot = tid & 63;
        const int kg = slot >> 4, lr = slot & 15;
        const short8 vals = *(const short8*)(&lrow[lr][kt * 32 + kg * 8]);
        *(short8*)(Abf + (((size_t)u * KT + kt) * 64 + slot) * 8) = vals;
    }
}

// Pure-MFMA pair GEMM over 4x4 batch-group tiles. No LDS, no barriers.
// 256 blocks x 1024 thr (16 waves). Off-diag tile (gi<gj): block=(wq=(t,cs),h);
// wave = (slot in [0,8), ch): pair i=4gi+h*2+(slot>>2), j=4gj+(slot&3),
// cols = cs*192 + ch*96 (6 dt frags). Diag blocks: 6 pairs + 2 zero-waves.
// acc = A@kv_i + (-A)@kv_j; rows dir0 -> out[i*B+j], dir1 -> -acc at [j*B+i].
__global__ __launch_bounds__(1024) void dgemm(const unsigned short* __restrict__ Abf,
                                              const unsigned short* __restrict__ kvTf,
                                              float* __restrict__ out) {
    const int bid = blockIdx.x;
    const int x = bid & 7, k = bid >> 3;      // XCD-bijective remap
    const int tid = threadIdx.x, wave = tid >> 6, lane = tid & 63;
    const int slot = wave >> 1, ch = wave & 1;

    int i, j, cs;
    if (k < 28) {
        const int wq = x + 8 * (k >> 1);      // [0,112)
        const int h = k & 1;
        int t = wq >> 2;
        cs = wq & 3;
        int tt = t, gi = 0;
        while (tt >= 7 - gi) { tt -= 7 - gi; ++gi; }
        const int gj = gi + 1 + tt;
        i = 4 * gi + h * 2 + (slot >> 2);
        j = 4 * gj + (slot & 3);
    } else {
        const int gt = x;
        cs = k - 28;
        if (slot >= 6) {
            // zero-fill two diagonal outputs' 96-col window
            const int dd0 = (slot - 6) * 2;
#pragma unroll
            for (int t2 = 0; t2 < 2; ++t2) {
                const int ii = 4 * gt + dd0 + t2;
                float* base = out + (size_t)(ii * B + ii) * NQ * D + cs * 192 + ch * 96;
#pragma unroll
                for (int q = 0; q < NQ; ++q) {
                    base[q * D + lane] = 0.f;
                    if (lane < 32) base[q * D + 64 + lane] = 0.f;
                }
            }
            return;
        }
        // pairs within group: (0,1),(0,2),(0,3),(1,2),(1,3),(2,3)
        const int a = (slot < 3) ? 0 : ((slot < 5) ? 1 : 2);
        const int bb = (slot < 3) ? (slot + 1) : ((slot < 5) ? (slot - 1) : 3);
        i = 4 * gt + a;
        j = 4 * gt + bb;
    }

    const int u = (i * (63 - i)) / 2 + (j - i - 1);
    const int dtb = cs * 12 + ch * 6;

    const unsigned short* Au = Abf + (size_t)u * KT * 512 + (size_t)lane * 8;
    const unsigned short* Ki = kvTf + ((size_t)i * 48 + dtb) * KT * 512 + (size_t)lane * 8;
    const unsigned short* Kj = kvTf + ((size_t)j * 48 + dtb) * KT * 512 + (size_t)lane * 8;

    f32x4 acc[6];
#pragma unroll
    for (int nf = 0; nf < 6; ++nf) {
        f32x4 z = {0.f, 0.f, 0.f, 0.f};
        acc[nf] = z;
    }

#pragma unroll
    for (int kt = 0; kt < KT; ++kt) {
        const short8 a8 = *(const short8*)(Au + (size_t)kt * 512);
        short8 na8;
#pragma unroll
        for (int e = 0; e < 8; ++e) na8[e] = (short)(a8[e] ^ (short)0x8000);
#pragma unroll
        for (int nf = 0; nf < 6; ++nf) {
            const short8 ki = *(const short8*)(Ki + ((size_t)nf * KT + kt) * 512);
            const short8 kj = *(const short8*)(Kj + ((size_t)nf * KT + kt) * 512);
            acc[nf] = __builtin_amdgcn_mfma_f32_16x16x32_bf16(a8,  ki, acc[nf], 0, 0, 0);
            acc[nf] = __builtin_amdgcn_mfma_f32_16x16x32_bf16(na8, kj, acc[nf], 0, 0, 0);
        }
    }

    // C layout: col = lane&15, row-in-tile = (lane>>4)*4 + reg
    const int kgrp = lane >> 4, dl = lane & 15;
    const int pij = i * B + j, pji = j * B + i;
#pragma unroll
    for (int reg = 0; reg < 4; ++reg) {
        const int r = kgrp * 4 + reg;
        const int dirr = r >> 3, qq = r & 7;
        const int p = dirr ? pji : pij;
        const float sgn = dirr ? -1.f : 1.f;
        float* op = out + ((size_t)p * NQ + qq) * D + cs * 192 + ch * 96 + dl;
#pragma unroll
        for (int nf = 0; nf < 6; ++nf) op[nf * 16] = sgn * acc[nf][reg];
    }
}

extern "C" void kernel_launch(void* const* d_in, const int* in_sizes, int n_in,
                              void* d_out, int out_size, void* d_ws, size_t ws_size,
                              hipStream_t stream) {
    const float* q_x     = (const float*)d_in[0];
    const float* kv_x    = (const float*)d_in[1];
    const float* ln_q_w  = (const float*)d_in[2];
    const float* ln_q_b  = (const float*)d_in[3];
    const float* ln_kv_w = (const float*)d_in[4];
    const float* ln_kv_b = (const float*)d_in[5];
    float* out = (float*)d_out;

    float* ws = (float*)d_ws;
    float* S  = ws;                                             // 32*8*196 f32
    unsigned short* kvTf = (unsigned short*)(ws + B * NQ * NP);  // 32*48*7*512 bf16
    unsigned short* Abf  = kvTf + (size_t)B * 48 * KT * 512;     // 496*7*512 bf16

    kv_fused<<<B * 14, 256, 0, stream>>>(q_x, ln_q_w, ln_q_b, kv_x, ln_kv_w, ln_kv_b, S, kvTf);
    aprep<<<(B * (B - 1)) / 2, 512, 0, stream>>>(S, Abf);
    dgemm<<<256, 1024, 0, stream>>>(Abf, kvTf, out);
}

// Round 11
// 46.695 us; speedup vs baseline: 1.5170x; 1.1452x over previous
//
#include <hip/hip_runtime.h>
#include <math.h>

constexpr int D  = 768;
constexpr int NQ = 8;
constexpr int B  = 32;
constexpr int NP = 196;      // n_patch
constexpr int KT = 7;        // K tiles of 32
constexpr int KP = KT * 32;  // 224 padded K
constexpr int TPAD = 776;    // LDS tile row stride (shorts)
constexpr int NTOFF = 28;    // off-diag 4x4-group tiles: C(8,2)
constexpr int NTILES = 32;   // + 4 diag-combo tiles (2 groups each)
constexpr float EPS = 1e-5f;
constexpr float INV_SQRT_D = 0.036084391824351615f;  // 1/sqrt(768)

typedef __attribute__((ext_vector_type(8))) short short8;
typedef __attribute__((ext_vector_type(4))) float f32x4;

__device__ __forceinline__ float wave_reduce_sum(float v) {
#pragma unroll
    for (int off = 32; off > 0; off >>= 1) v += __shfl_xor(v, off, 64);
    return v;
}
__device__ __forceinline__ float wave_reduce_max(float v) {
#pragma unroll
    for (int off = 32; off > 0; off >>= 1) v = fmaxf(v, __shfl_xor(v, off, 64));
    return v;
}

__device__ __forceinline__ unsigned short f2bf(float x) {
    union { float f; unsigned u; } c; c.f = x;
    unsigned r = c.u + 0x7fffu + ((c.u >> 16) & 1u);   // RNE
    return (unsigned short)(r >> 16);
}

// Fused: LN(q) in-reg + LN(kv 16-row half-tile) + scores S + frag-layout pack.
// kvTf[b][dt:48][kt:7][slot:64][e:8], value = kvn[kt*32+kg*8+e][dt*16+dl],
// slot = kg*16+dl.  One block per (b, h) with h in [0,14): rows [h*16,h*16+16).
__global__ __launch_bounds__(256) void kv_fused(const float* __restrict__ q_x,
                                                const float* __restrict__ qw,
                                                const float* __restrict__ qb,
                                                const float* __restrict__ kv_x,
                                                const float* __restrict__ kw,
                                                const float* __restrict__ kb,
                                                float* __restrict__ S,
                                                unsigned short* __restrict__ kvTf) {
    const int b = blockIdx.x / 14;
    const int h = blockIdx.x % 14;
    const int kt = h >> 1;
    const int kgbase = (h & 1) * 2;
    const int tid = threadIdx.x, wave = tid >> 6, lane = tid & 63;
    __shared__ unsigned short tile[16][TPAD];  // 24.8 KB

    const bool live = (h * 16) < NP;

    float wv[12], bv[12];
#pragma unroll
    for (int c = 0; c < 12; ++c) { wv[c] = kw[lane + 64 * c]; bv[c] = kb[lane + 64 * c]; }

    float qreg[NQ][12];
    if (live) {
        float wqv[12], bqv[12];
#pragma unroll
        for (int c = 0; c < 12; ++c) { wqv[c] = qw[lane + 64 * c]; bqv[c] = qb[lane + 64 * c]; }
#pragma unroll
        for (int q = 0; q < NQ; ++q) {
            float v[12];
            float s = 0.f;
#pragma unroll
            for (int c = 0; c < 12; ++c) { v[c] = q_x[q * D + lane + 64 * c]; s += v[c]; }
            s = wave_reduce_sum(s);
            const float mean = s * (1.0f / D);
            float ss = 0.f;
#pragma unroll
            for (int c = 0; c < 12; ++c) { v[c] -= mean; ss += v[c] * v[c]; }
            ss = wave_reduce_sum(ss);
            const float rs = rsqrtf(ss * (1.0f / D) + EPS);
#pragma unroll
            for (int c = 0; c < 12; ++c) qreg[q][c] = v[c] * rs * wqv[c] + bqv[c];
        }
    }

    for (int r = 0; r < 4; ++r) {
        const int nl = wave * 4 + r;
        const int n  = h * 16 + nl;
        if (n < NP) {
            const float* xr = kv_x + ((size_t)b * NP + n) * D;
            float v[12];
            float s = 0.f;
#pragma unroll
            for (int c = 0; c < 12; ++c) { v[c] = xr[lane + 64 * c]; s += v[c]; }
            s = wave_reduce_sum(s);
            const float mean = s * (1.0f / D);
            float ss = 0.f;
#pragma unroll
            for (int c = 0; c < 12; ++c) { v[c] -= mean; ss += v[c] * v[c]; }
            ss = wave_reduce_sum(ss);
            const float rs = rsqrtf(ss * (1.0f / D) + EPS);
            float y[12];
#pragma unroll
            for (int c = 0; c < 12; ++c) {
                y[c] = v[c] * rs * wv[c] + bv[c];
                tile[nl][lane + 64 * c] = f2bf(y[c]);
            }
#pragma unroll
            for (int q = 0; q < NQ; ++q) {
                float dq = 0.f;
#pragma unroll
                for (int c = 0; c < 12; ++c) dq += y[c] * qreg[q][c];
                dq = wave_reduce_sum(dq);
                if (lane == 0) S[((size_t)b * NQ + q) * NP + n] = dq * INV_SQRT_D;
            }
        } else {
#pragma unroll
            for (int c = 0; c < 12; ++c) tile[nl][lane + 64 * c] = 0;
        }
    }
    __syncthreads();

    // frag-layout store: 48 dt * 32 local slots = 1536 chunks of 16B, 6/thread.
#pragma unroll
    for (int rep = 0; rep < 6; ++rep) {
        const int chunk = rep * 256 + tid;
        const int dt = chunk >> 5, ls = chunk & 31;
        const int hi = ls >> 4, dl = ls & 15;
        const int kg = kgbase + hi;
        short8 vals;
#pragma unroll
        for (int e = 0; e < 8; ++e)
            vals[e] = (short)tile[hi * 8 + e][dt * 16 + dl];
        *(short8*)(kvTf + ((((size_t)b * 48 + dt) * KT + kt) * 64 + kg * 16 + dl) * 8) = vals;
    }
}

// Softmax once per unordered pair u={i<j}: 16 rows r = dir*8+q
// (dir0 = softmax(S_i - S_j), dir1 = softmax(S_j - S_i)), written bf16 in
// MFMA-frag layout Abf[u][kt:7][slot:64][e:8], slot = kg*16 + r.
__global__ __launch_bounds__(512) void aprep(const float* __restrict__ S,
                                             unsigned short* __restrict__ Abf) {
    const int u = blockIdx.x;
    int uu = u, i = 0;
    while (uu >= 31 - i) { uu -= 31 - i; ++i; }
    const int j = i + 1 + uu;

    const int tid = threadIdx.x, wave = tid >> 6, lane = tid & 63;
    __shared__ unsigned short lrow[16][KP];  // 7 KB

    for (int jj = 0; jj < 2; ++jj) {
        const int r = wave * 2 + jj;          // 0..15
        const int dir = r >> 3, q = r & 7;
        const float* Sa = S + ((size_t)(dir ? j : i) * NQ + q) * NP;
        const float* Sb = S + ((size_t)(dir ? i : j) * NQ + q) * NP;
        float v[4];
        float m = -1e30f;
#pragma unroll
        for (int c = 0; c < 4; ++c) {
            const int n = lane + 64 * c;
            v[c] = (n < NP) ? (Sa[n] - Sb[n]) : -1e30f;
            m = fmaxf(m, v[c]);
        }
        m = wave_reduce_max(m);
        float e[4];
        float sum = 0.f;
#pragma unroll
        for (int c = 0; c < 4; ++c) {
            const int n = lane + 64 * c;
            e[c] = (n < NP) ? __expf(v[c] - m) : 0.f;
            sum += e[c];
        }
        sum = wave_reduce_sum(sum);
        const float rinv = 1.0f / sum;
#pragma unroll
        for (int c = 0; c < 4; ++c) {
            const int n = lane + 64 * c;
            if (n < KP) lrow[r][n] = (n < NP) ? f2bf(e[c] * rinv) : (unsigned short)0;
        }
    }
    __syncthreads();

    // frag write: 7 kt * 64 slots = 448 chunks of 16B
    if (tid < 448) {
        const int kt = tid >> 6, slot = tid & 63;
        const int kg = slot >> 4, lr = slot & 15;
        const short8 vals = *(const short8*)(&lrow[lr][kt * 32 + kg * 8]);
        *(short8*)(Abf + (((size_t)u * KT + kt) * 64 + slot) * 8) = vals;
    }
}

// LDS-staged pair GEMM over 4x4 group tiles, double-buffered global_load_lds.
// Block = (tile t, cs of 8): 96-col slice (6 dt). 16 waves.
//  t < 28: off-diag groups (gi<gj): 16 pairs, wave = pair (i-loc = w>>2,
//          j-loc = w&3). 8 panels staged: p<4 -> 4gi+p, else 4gj+(p-4).
//  t >= 28: diag-combo (groups 2(t-28), 2(t-28)+1): waves 0-5 group0 pairs,
//          6-11 group1 pairs, 12-15 zero-fill the 8 diagonal outputs.
//          Panels p -> b = 8(t-28)+p.
// acc = A@kv_i + (-A)@kv_j; rows dir0 -> out[i*B+j], dir1 -> -acc at [j*B+i].
// XCD locality: bid = t*8+cs, XCD = bid%8 = cs -> per-XCD kv slice 1.34 MB.
__global__ __launch_bounds__(1024) void dgemm(const unsigned short* __restrict__ Abf,
                                              const unsigned short* __restrict__ kvTf,
                                              float* __restrict__ out) {
    const int bid = blockIdx.x;
    const int t = bid >> 3, cs = bid & 7;
    const int tid = threadIdx.x, wave = tid >> 6, lane = tid & 63;

    __shared__ unsigned short stg[2][8][6][64][8];  // 96 KB double-buffered

    const bool offd = (t < NTOFF);
    int gi = 0, gj = 0;
    if (offd) {
        int tt = t, a = 0;
        while (tt >= 7 - a) { tt -= 7 - a; ++a; }
        gi = a; gj = a + 1 + tt;
    }
    const int dbase = 8 * (t - NTOFF);

    // ---- pair decode for this wave ----
    int i = 0, j = 0, pi = 0, pj = 0;
    bool compute = true;
    if (offd) {
        pi = wave >> 2; pj = 4 + (wave & 3);
        i = 4 * gi + pi; j = 4 * gj + (wave & 3);
    } else if (wave < 12) {
        const int g = wave / 6, w6 = wave - 6 * g;
        // pairs within 4-group: (0,1),(0,2),(0,3),(1,2),(1,3),(2,3)
        const int a = (w6 < 3) ? 0 : ((w6 < 5) ? 1 : 2);
        const int bb = (w6 < 3) ? (w6 + 1) : ((w6 < 5) ? (w6 - 1) : 3);
        pi = 4 * g + a; pj = 4 * g + bb;
        i = dbase + pi; j = dbase + pj;
    } else {
        compute = false;
        // zero-fill 8 diagonal outputs' 96-col window (2 per idle wave)
        const int zw = wave - 12;
#pragma unroll
        for (int t2 = 0; t2 < 2; ++t2) {
            const int ii = dbase + zw * 2 + t2;
            float* base = out + (size_t)(ii * B + ii) * NQ * D + cs * 96;
            for (int e = lane; e < NQ * 96; e += 64) {
                const int q = e / 96, c = e - q * 96;
                base[q * D + c] = 0.f;
            }
        }
    }

    // ---- A prefetch to registers (7 KB per pair) ----
    const int u = (i * (63 - i)) / 2 + (j - i - 1);
    short8 areg[KT];
    if (compute) {
        const unsigned short* Au = Abf + (size_t)u * KT * 512 + (size_t)lane * 8;
#pragma unroll
        for (int kt = 0; kt < KT; ++kt) areg[kt] = *(const short8*)(Au + (size_t)kt * 512);
    }

    // ---- staging assignment: wave stages panel sp = wave>>1, dt [sd0,sd0+3) ----
    const int sp = wave >> 1;
    const int sd0 = (wave & 1) * 3;
    const int sb = offd ? ((sp < 4) ? (4 * gi + sp) : (4 * gj + sp - 4)) : (dbase + sp);
    const unsigned short* gbase =
        kvTf + (((size_t)sb * 48 + cs * 6 + sd0) * KT) * 512 + (size_t)lane * 8;

    f32x4 acc[6];
#pragma unroll
    for (int nf = 0; nf < 6; ++nf) {
        f32x4 z = {0.f, 0.f, 0.f, 0.f};
        acc[nf] = z;
    }

    // prologue: stage kt=0 into buf 0
#pragma unroll
    for (int r = 0; r < 3; ++r)
        __builtin_amdgcn_global_load_lds(
            (const __attribute__((address_space(1))) void*)(gbase + ((size_t)r * KT) * 512),
            (__attribute__((address_space(3))) void*)(&stg[0][sp][sd0 + r][0][0]), 16, 0, 0);
    __syncthreads();

    int buf = 0;
    for (int kt = 0; kt < KT; ++kt) {
        if (kt + 1 < KT) {
#pragma unroll
            for (int r = 0; r < 3; ++r)
                __builtin_amdgcn_global_load_lds(
                    (const __attribute__((address_space(1))) void*)(gbase + ((size_t)r * KT + kt + 1) * 512),
                    (__attribute__((address_space(3))) void*)(&stg[buf ^ 1][sp][sd0 + r][0][0]), 16, 0, 0);
        }
        if (compute) {
            const short8 a8 = areg[kt];
            short8 na8;
#pragma unroll
            for (int e = 0; e < 8; ++e) na8[e] = (short)(a8[e] ^ (short)0x8000);
#pragma unroll
            for (int nf = 0; nf < 6; ++nf) {
                const short8 ki = *(const short8*)(&stg[buf][pi][nf][lane][0]);
                const short8 kj = *(const short8*)(&stg[buf][pj][nf][lane][0]);
                acc[nf] = __builtin_amdgcn_mfma_f32_16x16x32_bf16(a8,  ki, acc[nf], 0, 0, 0);
                acc[nf] = __builtin_amdgcn_mfma_f32_16x16x32_bf16(na8, kj, acc[nf], 0, 0, 0);
            }
        }
        __syncthreads();
        buf ^= 1;
    }

    // ---- epilogue: C row-in-tile = (lane>>4)*4 + reg, col = lane&15 ----
    if (compute) {
        const int kgrp = lane >> 4, dl = lane & 15;
        const int pij = i * B + j, pji = j * B + i;
#pragma unroll
        for (int reg = 0; reg < 4; ++reg) {
            const int r = kgrp * 4 + reg;
            const int dirr = r >> 3, qq = r & 7;
            const int p = dirr ? pji : pij;
            const float sgn = dirr ? -1.f : 1.f;
            float* op = out + ((size_t)p * NQ + qq) * D + cs * 96 + dl;
#pragma unroll
            for (int nf = 0; nf < 6; ++nf) op[nf * 16] = sgn * acc[nf][reg];
        }
    }
}

extern "C" void kernel_launch(void* const* d_in, const int* in_sizes, int n_in,
                              void* d_out, int out_size, void* d_ws, size_t ws_size,
                              hipStream_t stream) {
    const float* q_x     = (const float*)d_in[0];
    const float* kv_x    = (const float*)d_in[1];
    const float* ln_q_w  = (const float*)d_in[2];
    const float* ln_q_b  = (const float*)d_in[3];
    const float* ln_kv_w = (const float*)d_in[4];
    const float* ln_kv_b = (const float*)d_in[5];
    float* out = (float*)d_out;

    float* ws = (float*)d_ws;
    float* S  = ws;                                             // 32*8*196 f32
    unsigned short* kvTf = (unsigned short*)(ws + B * NQ * NP);  // 32*48*7*512 bf16
    unsigned short* Abf  = kvTf + (size_t)B * 48 * KT * 512;     // 496*7*512 bf16

    kv_fused<<<B * 14, 256, 0, stream>>>(q_x, ln_q_w, ln_q_b, kv_x, ln_kv_w, ln_kv_b, S, kvTf);
    aprep<<<(B * (B - 1)) / 2, 512, 0, stream>>>(S, Abf);
    dgemm<<<NTILES * 8, 1024, 0, stream>>>(Abf, kvTf, out);
}

// Round 12
// 38.774 us; speedup vs baseline: 1.8269x; 1.2043x over previous
//
#include <hip/hip_runtime.h>
#include <math.h>

constexpr int D  = 768;
constexpr int NQ = 8;
constexpr int B  = 32;
constexpr int NP = 196;      // n_patch
constexpr int KT = 7;        // K tiles of 32
constexpr int KP = KT * 32;  // 224 padded K
constexpr int TPAD = 776;    // LDS tile row stride (shorts); 1552B = 2-way banks
constexpr int NTOFF = 28;    // off-diag 4x4-group tiles: C(8,2)
constexpr int NTILES = 32;   // + 4 diag-combo tiles (2 groups each)
constexpr float EPS = 1e-5f;
constexpr float INV_SQRT_D = 0.036084391824351615f;  // 1/sqrt(768)

typedef __attribute__((ext_vector_type(8))) short short8;
typedef __attribute__((ext_vector_type(4))) float f32x4;

__device__ __forceinline__ float wave_reduce_sum(float v) {
#pragma unroll
    for (int off = 32; off > 0; off >>= 1) v += __shfl_xor(v, off, 64);
    return v;
}
__device__ __forceinline__ float wave_reduce_max(float v) {
#pragma unroll
    for (int off = 32; off > 0; off >>= 1) v = fmaxf(v, __shfl_xor(v, off, 64));
    return v;
}

__device__ __forceinline__ unsigned short f2bf(float x) {
    union { float f; unsigned u; } c; c.f = x;
    unsigned r = c.u + 0x7fffu + ((c.u >> 16) & 1u);   // RNE
    return (unsigned short)(r >> 16);
}

// Fused: LN(q)->qbf LDS + LN(kv 16-row half-tile) + MFMA scores S + frag pack.
// kvTf[b][dt:48][kt:7][slot:64][e:8], value = kvn[kt*32+kg*8+e][dt*16+dl].
// One block per (b, h), h in [0,14): rows [h*16, h*16+16).
__global__ __launch_bounds__(256) void kv_fused(const float* __restrict__ q_x,
                                                const float* __restrict__ qw,
                                                const float* __restrict__ qb,
                                                const float* __restrict__ kv_x,
                                                const float* __restrict__ kw,
                                                const float* __restrict__ kb,
                                                float* __restrict__ S,
                                                unsigned short* __restrict__ kvTf) {
    const int b = blockIdx.x / 14;
    const int h = blockIdx.x % 14;
    const int kt = h >> 1;
    const int kgbase = (h & 1) * 2;
    const int tid = threadIdx.x, wave = tid >> 6, lane = tid & 63;
    __shared__ unsigned short tile[16][TPAD];  // 24.8 KB
    __shared__ unsigned short qbf[16][TPAD];   // 24.8 KB (rows 8-15 unused)

    const bool live = (h * 16) < NP;

    float wv[12], bv[12];
#pragma unroll
    for (int c = 0; c < 12; ++c) { wv[c] = kw[lane + 64 * c]; bv[c] = kb[lane + 64 * c]; }

    // q-LN -> qbf (bf16), distributed: wave w handles q rows {2w, 2w+1}
    if (live && wave < 4) {
        float wq[12], bq[12];
#pragma unroll
        for (int c = 0; c < 12; ++c) { wq[c] = qw[lane + 64 * c]; bq[c] = qb[lane + 64 * c]; }
        for (int rr = 0; rr < 2; ++rr) {
            const int q = wave * 2 + rr;
            float v[12];
            float s = 0.f;
#pragma unroll
            for (int c = 0; c < 12; ++c) { v[c] = q_x[q * D + lane + 64 * c]; s += v[c]; }
            s = wave_reduce_sum(s);
            const float mean = s * (1.0f / D);
            float ss = 0.f;
#pragma unroll
            for (int c = 0; c < 12; ++c) { v[c] -= mean; ss += v[c] * v[c]; }
            ss = wave_reduce_sum(ss);
            const float rs = rsqrtf(ss * (1.0f / D) + EPS);
#pragma unroll
            for (int c = 0; c < 12; ++c)
                qbf[q][lane + 64 * c] = f2bf(v[c] * rs * wq[c] + bq[c]);
        }
    }

    // kv-LN -> tile (bf16)
    for (int r = 0; r < 4; ++r) {
        const int nl = wave * 4 + r;
        const int n  = h * 16 + nl;
        if (n < NP) {
            const float* xr = kv_x + ((size_t)b * NP + n) * D;
            float v[12];
            float s = 0.f;
#pragma unroll
            for (int c = 0; c < 12; ++c) { v[c] = xr[lane + 64 * c]; s += v[c]; }
            s = wave_reduce_sum(s);
            const float mean = s * (1.0f / D);
            float ss = 0.f;
#pragma unroll
            for (int c = 0; c < 12; ++c) { v[c] -= mean; ss += v[c] * v[c]; }
            ss = wave_reduce_sum(ss);
            const float rs = rsqrtf(ss * (1.0f / D) + EPS);
#pragma unroll
            for (int c = 0; c < 12; ++c)
                tile[nl][lane + 64 * c] = f2bf(v[c] * rs * wv[c] + bv[c]);
        } else {
#pragma unroll
            for (int c = 0; c < 12; ++c) tile[nl][lane + 64 * c] = 0;
        }
    }
    __syncthreads();

    // frag-layout store: 48 dt * 32 local slots = 1536 chunks of 16B, 6/thread.
#pragma unroll
    for (int rep = 0; rep < 6; ++rep) {
        const int chunk = rep * 256 + tid;
        const int dt = chunk >> 5, ls = chunk & 31;
        const int hi = ls >> 4, dl = ls & 15;
        const int kg = kgbase + hi;
        short8 vals;
#pragma unroll
        for (int e = 0; e < 8; ++e)
            vals[e] = (short)tile[hi * 8 + e][dt * 16 + dl];
        *(short8*)(kvTf + ((((size_t)b * 48 + dt) * KT + kt) * 64 + kg * 16 + dl) * 8) = vals;
    }

    // scores via MFMA: S16x8 = tile(16 x 768) x qbf^T, wave 0 only.
    // A-frag: lane -> tile[lane&15][k2*32+(lane>>4)*8+e]; B-frag same from qbf
    // (cols 8-15 garbage, discarded). C: col=lane&15 (q), row=(lane>>4)*4+reg.
    if (live && wave == 0) {
        f32x4 s0 = {0.f, 0.f, 0.f, 0.f}, s1 = {0.f, 0.f, 0.f, 0.f};
        const int ar = lane & 15, akg = lane >> 4;
#pragma unroll
        for (int k2 = 0; k2 < 24; k2 += 2) {
            s0 = __builtin_amdgcn_mfma_f32_16x16x32_bf16(
                *(const short8*)&tile[ar][k2 * 32 + akg * 8],
                *(const short8*)&qbf[ar][k2 * 32 + akg * 8], s0, 0, 0, 0);
            s1 = __builtin_amdgcn_mfma_f32_16x16x32_bf16(
                *(const short8*)&tile[ar][(k2 + 1) * 32 + akg * 8],
                *(const short8*)&qbf[ar][(k2 + 1) * 32 + akg * 8], s1, 0, 0, 0);
        }
        s0 = s0 + s1;
        const int q = lane & 15;
        if (q < NQ) {
#pragma unroll
            for (int reg = 0; reg < 4; ++reg) {
                const int n = h * 16 + akg * 4 + reg;
                if (n < NP) S[((size_t)b * NQ + q) * NP + n] = s0[reg] * INV_SQRT_D;
            }
        }
    }
}

// Softmax once per unordered pair u={i<j}: 16 rows r = dir*8+q
// (dir0 = softmax(S_i - S_j), dir1 = softmax(S_j - S_i)), written bf16 in
// MFMA-frag layout Abf[u][kt:7][slot:64][e:8], slot = kg*16 + r.
__global__ __launch_bounds__(512) void aprep(const float* __restrict__ S,
                                             unsigned short* __restrict__ Abf) {
    const int u = blockIdx.x;
    int uu = u, i = 0;
    while (uu >= 31 - i) { uu -= 31 - i; ++i; }
    const int j = i + 1 + uu;

    const int tid = threadIdx.x, wave = tid >> 6, lane = tid & 63;
    __shared__ unsigned short lrow[16][KP];  // 7 KB

    for (int jj = 0; jj < 2; ++jj) {
        const int r = wave * 2 + jj;          // 0..15
        const int dir = r >> 3, q = r & 7;
        const float* Sa = S + ((size_t)(dir ? j : i) * NQ + q) * NP;
        const float* Sb = S + ((size_t)(dir ? i : j) * NQ + q) * NP;
        float v[4];
        float m = -1e30f;
#pragma unroll
        for (int c = 0; c < 4; ++c) {
            const int n = lane + 64 * c;
            v[c] = (n < NP) ? (Sa[n] - Sb[n]) : -1e30f;
            m = fmaxf(m, v[c]);
        }
        m = wave_reduce_max(m);
        float e[4];
        float sum = 0.f;
#pragma unroll
        for (int c = 0; c < 4; ++c) {
            const int n = lane + 64 * c;
            e[c] = (n < NP) ? __expf(v[c] - m) : 0.f;
            sum += e[c];
        }
        sum = wave_reduce_sum(sum);
        const float rinv = 1.0f / sum;
#pragma unroll
        for (int c = 0; c < 4; ++c) {
            const int n = lane + 64 * c;
            if (n < KP) lrow[r][n] = (n < NP) ? f2bf(e[c] * rinv) : (unsigned short)0;
        }
    }
    __syncthreads();

    if (tid < 448) {
        const int kt = tid >> 6, slot = tid & 63;
        const int kg = slot >> 4, lr = slot & 15;
        const short8 vals = *(const short8*)(&lrow[lr][kt * 32 + kg * 8]);
        *(short8*)(Abf + (((size_t)u * KT + kt) * 64 + slot) * 8) = vals;
    }
}

// LDS-staged pair GEMM, double-buffered global_load_lds, 2 pairs/wave.
// Block = (tile t, cs of 8): 96-col slice. 16 waves.
//  t < 28 (off-diag, groups gi<gj): wave = (pi, bh, dth): pairs
//    (i=4gi+pi, j=4gj+2bh) and (i, j+1), dt half = dth*3. Shared ki read.
//  t >= 28 (diag-combo): waves 0-11: ps=w>>1 picks 2 pairs from the 6-enum
//    of group g=ps/3; waves 12-15 zero-fill the 8 diagonal outputs.
// acc = A@kv_i + (-A)@kv_j; rows dir0 -> out[i*B+j], dir1 -> -acc at [j*B+i].
__global__ __launch_bounds__(1024) void dgemm(const unsigned short* __restrict__ Abf,
                                              const unsigned short* __restrict__ kvTf,
                                              float* __restrict__ out) {
    const int bid = blockIdx.x;
    const int t = bid >> 3, cs = bid & 7;
    const int tid = threadIdx.x, wave = tid >> 6, lane = tid & 63;

    __shared__ unsigned short stg[2][8][6][64][8];  // 96 KB double-buffered

    const bool offd = (t < NTOFF);
    int gi = 0, gj = 0;
    if (offd) {
        int tt = t, a = 0;
        while (tt >= 7 - a) { tt -= 7 - a; ++a; }
        gi = a; gj = a + 1 + tt;
    }
    const int dbase = 8 * (t - NTOFF);

    // ---- wave decode: 2 pairs + dt-half ----
    int i0 = 0, j0 = 0, i1 = 0, j1 = 0;
    int p0i = 0, p0j = 0, p1i = 0, p1j = 0, dth = 0;
    bool compute = true;
    if (offd) {
        const int pi = wave >> 2, bh = (wave >> 1) & 1;
        dth = wave & 1;
        i0 = 4 * gi + pi; j0 = 4 * gj + 2 * bh;
        i1 = i0;          j1 = j0 + 1;
        p0i = pi; p0j = 4 + 2 * bh; p1i = pi; p1j = p0j + 1;
    } else if (wave < 12) {
        const int ps = wave >> 1;
        dth = wave & 1;
        const int g = ps / 3, k3 = ps - 3 * g;
        const int ea[6] = {0, 0, 0, 1, 1, 2}, eb[6] = {1, 2, 3, 2, 3, 3};
        const int e0 = 2 * k3, e1 = e0 + 1;
        p0i = 4 * g + ea[e0]; p0j = 4 * g + eb[e0];
        p1i = 4 * g + ea[e1]; p1j = 4 * g + eb[e1];
        i0 = dbase + p0i; j0 = dbase + p0j;
        i1 = dbase + p1i; j1 = dbase + p1j;
    } else {
        compute = false;
        const int zw = wave - 12;
#pragma unroll
        for (int t2 = 0; t2 < 2; ++t2) {
            const int ii = dbase + zw * 2 + t2;
            float* base = out + (size_t)(ii * B + ii) * NQ * D + cs * 96;
            for (int e = lane; e < NQ * 96; e += 64) {
                const int q = e / 96, c = e - q * 96;
                base[q * D + c] = 0.f;
            }
        }
    }

    // ---- A prefetch to registers (2 pairs x 7 KB) ----
    short8 areg0[KT], areg1[KT];
    if (compute) {
        const int u0 = (i0 * (63 - i0)) / 2 + (j0 - i0 - 1);
        const int u1 = (i1 * (63 - i1)) / 2 + (j1 - i1 - 1);
        const unsigned short* Au0 = Abf + (size_t)u0 * KT * 512 + (size_t)lane * 8;
        const unsigned short* Au1 = Abf + (size_t)u1 * KT * 512 + (size_t)lane * 8;
#pragma unroll
        for (int kt = 0; kt < KT; ++kt) {
            areg0[kt] = *(const short8*)(Au0 + (size_t)kt * 512);
            areg1[kt] = *(const short8*)(Au1 + (size_t)kt * 512);
        }
    }

    // ---- staging: wave stages panel sp = wave>>1, dt [sd0,sd0+3) ----
    const int sp = wave >> 1;
    const int sd0 = (wave & 1) * 3;
    const int sb = offd ? ((sp < 4) ? (4 * gi + sp) : (4 * gj + sp - 4)) : (dbase + sp);
    const unsigned short* gbase =
        kvTf + (((size_t)sb * 48 + cs * 6 + sd0) * KT) * 512 + (size_t)lane * 8;

    f32x4 acc0[3], acc1[3];
#pragma unroll
    for (int nf = 0; nf < 3; ++nf) {
        f32x4 z = {0.f, 0.f, 0.f, 0.f};
        acc0[nf] = z; acc1[nf] = z;
    }

#pragma unroll
    for (int r = 0; r < 3; ++r)
        __builtin_amdgcn_global_load_lds(
            (const __attribute__((address_space(1))) void*)(gbase + ((size_t)r * KT) * 512),
            (__attribute__((address_space(3))) void*)(&stg[0][sp][sd0 + r][0][0]), 16, 0, 0);
    __syncthreads();

    int buf = 0;
    for (int kt = 0; kt < KT; ++kt) {
        if (kt + 1 < KT) {
#pragma unroll
            for (int r = 0; r < 3; ++r)
                __builtin_amdgcn_global_load_lds(
                    (const __attribute__((address_space(1))) void*)(gbase + ((size_t)r * KT + kt + 1) * 512),
                    (__attribute__((address_space(3))) void*)(&stg[buf ^ 1][sp][sd0 + r][0][0]), 16, 0, 0);
        }
        if (compute) {
            const short8 a0 = areg0[kt], a1 = areg1[kt];
            short8 na0, na1;
#pragma unroll
            for (int e = 0; e < 8; ++e) {
                na0[e] = (short)(a0[e] ^ (short)0x8000);
                na1[e] = (short)(a1[e] ^ (short)0x8000);
            }
            if (offd) {  // shared ki: 9 ds_reads feed 12 MFMAs
#pragma unroll
                for (int nf = 0; nf < 3; ++nf) {
                    const short8 ki  = *(const short8*)(&stg[buf][p0i][dth * 3 + nf][lane][0]);
                    const short8 kj0 = *(const short8*)(&stg[buf][p0j][dth * 3 + nf][lane][0]);
                    const short8 kj1 = *(const short8*)(&stg[buf][p1j][dth * 3 + nf][lane][0]);
                    acc0[nf] = __builtin_amdgcn_mfma_f32_16x16x32_bf16(a0,  ki,  acc0[nf], 0, 0, 0);
                    acc0[nf] = __builtin_amdgcn_mfma_f32_16x16x32_bf16(na0, kj0, acc0[nf], 0, 0, 0);
                    acc1[nf] = __builtin_amdgcn_mfma_f32_16x16x32_bf16(a1,  ki,  acc1[nf], 0, 0, 0);
                    acc1[nf] = __builtin_amdgcn_mfma_f32_16x16x32_bf16(na1, kj1, acc1[nf], 0, 0, 0);
                }
            } else {
#pragma unroll
                for (int nf = 0; nf < 3; ++nf) {
                    const short8 k0i = *(const short8*)(&stg[buf][p0i][dth * 3 + nf][lane][0]);
                    const short8 k0j = *(const short8*)(&stg[buf][p0j][dth * 3 + nf][lane][0]);
                    const short8 k1i = *(const short8*)(&stg[buf][p1i][dth * 3 + nf][lane][0]);
                    const short8 k1j = *(const short8*)(&stg[buf][p1j][dth * 3 + nf][lane][0]);
                    acc0[nf] = __builtin_amdgcn_mfma_f32_16x16x32_bf16(a0,  k0i, acc0[nf], 0, 0, 0);
                    acc0[nf] = __builtin_amdgcn_mfma_f32_16x16x32_bf16(na0, k0j, acc0[nf], 0, 0, 0);
                    acc1[nf] = __builtin_amdgcn_mfma_f32_16x16x32_bf16(a1,  k1i, acc1[nf], 0, 0, 0);
                    acc1[nf] = __builtin_amdgcn_mfma_f32_16x16x32_bf16(na1, k1j, acc1[nf], 0, 0, 0);
                }
            }
        }
        __syncthreads();
        buf ^= 1;
    }

    // ---- epilogue: C row-in-tile = (lane>>4)*4 + reg, col = lane&15 ----
    if (compute) {
        const int kgrp = lane >> 4, dl = lane & 15;
        const int colb = cs * 96 + dth * 48 + dl;
#pragma unroll
        for (int pr = 0; pr < 2; ++pr) {
            const int i = pr ? i1 : i0, j = pr ? j1 : j0;
            const f32x4* acc = pr ? acc1 : acc0;
            const int pij = i * B + j, pji = j * B + i;
#pragma unroll
            for (int reg = 0; reg < 4; ++reg) {
                const int r = kgrp * 4 + reg;
                const int dirr = r >> 3, qq = r & 7;
                const int p = dirr ? pji : pij;
                const float sgn = dirr ? -1.f : 1.f;
                float* op = out + ((size_t)p * NQ + qq) * D + colb;
#pragma unroll
                for (int nf = 0; nf < 3; ++nf) op[nf * 16] = sgn * acc[nf][reg];
            }
        }
    }
}

extern "C" void kernel_launch(void* const* d_in, const int* in_sizes, int n_in,
                              void* d_out, int out_size, void* d_ws, size_t ws_size,
                              hipStream_t stream) {
    const float* q_x     = (const float*)d_in[0];
    const float* kv_x    = (const float*)d_in[1];
    const float* ln_q_w  = (const float*)d_in[2];
    const float* ln_q_b  = (const float*)d_in[3];
    const float* ln_kv_w = (const float*)d_in[4];
    const float* ln_kv_b = (const float*)d_in[5];
    float* out = (float*)d_out;

    float* ws = (float*)d_ws;
    float* S  = ws;                                             // 32*8*196 f32
    unsigned short* kvTf = (unsigned short*)(ws + B * NQ * NP);  // 32*48*7*512 bf16
    unsigned short* Abf  = kvTf + (size_t)B * 48 * KT * 512;     // 496*7*512 bf16

    kv_fused<<<B * 14, 256, 0, stream>>>(q_x, ln_q_w, ln_q_b, kv_x, ln_kv_w, ln_kv_b, S, kvTf);
    aprep<<<(B * (B - 1)) / 2, 512, 0, stream>>>(S, Abf);
    dgemm<<<NTILES * 8, 1024, 0, stream>>>(Abf, kvTf, out);
}